// Round 2
// baseline (72.599 us; speedup 1.0000x reference)
//
#include <hip/hip_runtime.h>

// Chamfer distance v5 (resubmit — prior rounds failed on GPU broker, not kernel).
// B=4, N=M=4096, D=3, fp32 in, scalar fp32 out.
//
// R5 = drop the LDS double-buffer entirely.
//   Theory: inputs are L2-resident (393 KB raw / 512 KB packed), so the
//   chunked global->LDS staging only added per-chunk vmcnt(0)+barrier stalls
//   (compiler can't sink ds_writes past ds_reads of the other buffer) and
//   ~17M lane-ops of redundant repacking per pass.
//   New structure:
//     (1) chamfer_pack: one-shot repack of both clouds to float4
//         (x, y, z, |p|^2) in workspace (512 KB, L2-resident).
//     (2) chamfer_pass: per wave, 8 held pts broadcast in registers
//         (folded as -2*h so inner stays 3 fma + min3/2pts); each lane
//         streams its 1/64 slice of all 4096 stream pts as coalesced
//         global_load_dwordx4 straight from L2. No LDS, no barriers
//         in the hot loop. shfl_xor min-reduce at the end.
//   Grid 1024 = 4 blocks/CU, 16 waves/CU; VALU floor ~6 us, L2 ~2 us.
//
// Workspace: 32768 * 16 B packed (512 KB) + 1024 * 4 B partials.

#define NPTS 4096
#define TILE 32     // held points per block
#define G    8      // held points per wave (broadcast across 64 lanes)

__global__ __launch_bounds__(256) void chamfer_pack(
    const float* __restrict__ coord, const float* __restrict__ gt,
    float4* __restrict__ packed)   // [0..16383]=coord, [16384..32767]=gt
{
    int i = blockIdx.x * 256 + threadIdx.x;          // 0..32767
    const float* src = (i < 16384) ? (coord + i * 3)
                                   : (gt + (i - 16384) * 3);
    float x = src[0], y = src[1], z = src[2];
    packed[i] = make_float4(x, y, z, fmaf(x, x, fmaf(y, y, z * z)));
}

__global__ __launch_bounds__(256, 4) void chamfer_pass(
    const float4* __restrict__ packed, float* __restrict__ partials)
{
    const float4* pc = packed;            // coord, 4*4096
    const float4* pg = packed + 16384;    // gt,    4*4096

    int bx   = blockIdx.x;
    int pass = bx >> 9;            // 0: held=gt/stream=coord, 1: reverse
    int r    = bx & 511;
    int b    = r >> 7;
    int tile = r & 127;            // 128 tiles of 32 held pts

    const float4* hb = (pass ? pc : pg) + b * NPTS;
    const float4* sb = (pass ? pg : pc) + b * NPTS;

    int tid = threadIdx.x;
    int hg  = tid >> 6;            // 0..3: which 8-held group (one per wave)
    int ph  = tid & 63;            // lane

    // ---- held points -> registers, folded as (-2x,-2y,-2z), |h|^2 ----
    // d^2 = h.w + (c.w + c.x*(-2hx) + c.y*(-2hy) + c.z*(-2hz))
    float hx[G], hy[G], hz[G], h2[G], mn[G];
    int h0 = tile * TILE + hg * G;
#pragma unroll
    for (int g = 0; g < G; ++g) {
        float4 h = hb[h0 + g];
        hx[g] = -2.f * h.x;
        hy[g] = -2.f * h.y;
        hz[g] = -2.f * h.z;
        h2[g] = h.w;
        mn[g] = INFINITY;
    }

    // ---- stream all 4096 pts, 2 per lane per iter, straight from L2 ----
    const float4* s = sb + ph;
#pragma unroll 8
    for (int it = 0; it < 32; ++it) {
        float4 c0 = s[it * 128];
        float4 c1 = s[it * 128 + 64];
#pragma unroll
        for (int g = 0; g < G; ++g) {
            float a = fmaf(c0.x, hx[g], c0.w);   // |c|^2 - 2 c.h
            a = fmaf(c0.y, hy[g], a);
            a = fmaf(c0.z, hz[g], a);
            float d = fmaf(c1.x, hx[g], c1.w);
            d = fmaf(c1.y, hy[g], d);
            d = fmaf(c1.z, hz[g], d);
            mn[g] = fminf(fminf(a, d), mn[g]);   // v_min3_f32
        }
    }

    // ---- min over 64 lanes, add |h|^2, sum over g ----
    __shared__ float bsum[4];
    float ssum = 0.f;
#pragma unroll
    for (int g = 0; g < G; ++g) {
        float v = mn[g];
        v = fminf(v, __shfl_xor(v, 32));
        v = fminf(v, __shfl_xor(v, 16));
        v = fminf(v, __shfl_xor(v, 8));
        v = fminf(v, __shfl_xor(v, 4));
        v = fminf(v, __shfl_xor(v, 2));
        v = fminf(v, __shfl_xor(v, 1));
        ssum += fmaxf(v + h2[g], 0.f);   // true d^2 >= 0; clamp fp cancellation
    }
    if (ph == 0) bsum[hg] = ssum;
    __syncthreads();
    if (tid == 0)
        partials[bx] = bsum[0] + bsum[1] + bsum[2] + bsum[3];
}

__global__ __launch_bounds__(256) void chamfer_final(
    const float* __restrict__ partials, float* __restrict__ out)
{
    __shared__ float wsum[4];
    int tid = threadIdx.x;
    float s = 0.f;
#pragma unroll
    for (int k = 0; k < 4; ++k)
        s += partials[k * 256 + tid];
#pragma unroll
    for (int off = 32; off > 0; off >>= 1)
        s += __shfl_down(s, off);
    if ((tid & 63) == 0) wsum[tid >> 6] = s;
    __syncthreads();
    if (tid == 0)
        out[0] = (wsum[0] + wsum[1] + wsum[2] + wsum[3]) * (1.0f / 16384.0f);
}

extern "C" void kernel_launch(void* const* d_in, const int* in_sizes, int n_in,
                              void* d_out, int out_size, void* d_ws, size_t ws_size,
                              hipStream_t stream) {
    const float* coord = (const float*)d_in[0];  // [4,4096,3]
    const float* gt    = (const float*)d_in[1];  // [4,4096,3]
    float4* packed   = (float4*)d_ws;                                  // 512 KB
    float*  partials = (float*)((char*)d_ws + 32768 * sizeof(float4)); // 1024 floats
    float*  out      = (float*)d_out;

    chamfer_pack<<<128, 256, 0, stream>>>(coord, gt, packed);
    chamfer_pass<<<1024, 256, 0, stream>>>(packed, partials);
    chamfer_final<<<1, 256, 0, stream>>>(partials, out);
}

// Round 4
// 72.563 us; speedup vs baseline: 1.0005x; 1.0005x over previous
//
#include <hip/hip_runtime.h>

// Chamfer distance v6 (resubmit — R3 slot failed on GPU broker, not kernel).
// B=4, N=M=4096, D=3, fp32 in, scalar fp32 out.
//
// Measured context (R5): timed window includes a fixed ~40 us harness poison
// of the 256 MB workspace (fillBufferAligned, 262144 KB WRITE_SIZE). Our
// kernels are the remaining ~30 us. R5's no-LDS pass made 4096 waves each
// stream the same 64 KB from L2 = 256 MB of L2 reads -> L2-broadcast-bound
// (~10 TB/s effective), 4.7x over the 6 us VALU floor.
//
// R6: stage the ENTIRE packed stream (4096 x float4 = 64 KB) into LDS once
// per block; ONE barrier; all 8 waves then compute purely from LDS.
//  - kills R5's L2 rebroadcast (32 MB total, ~1 us)
//  - kills R4's per-chunk vmcnt(0)+barrier drains (no chunks)
//  - zero repack VALU (pack kernel pre-computes (x,y,z,|p|^2))
// Block = 512 thr (8 waves), TILE=64 held pts (G=8/wave), grid 512,
// 2 blocks/CU (64 KB LDS cap), 4 waves/SIMD.
// Per-CU budget: VALU 6.0 us, LDS pipe 5.1 us (ds_read_b128 contiguous,
// conflict-free), L2 ~1 us -> VALU-bound, pass ~8-9 us predicted.
//
// Workspace: 32768 * 16 B packed (512 KB) + 512 * 4 B partials.

#define NPTS 4096
#define TILE 64     // held points per block
#define G    8      // held points per wave (broadcast across 64 lanes)

__global__ __launch_bounds__(256) void chamfer_pack(
    const float* __restrict__ coord, const float* __restrict__ gt,
    float4* __restrict__ packed)   // [0..16383]=coord, [16384..32767]=gt
{
    int i = blockIdx.x * 256 + threadIdx.x;          // 0..32767
    const float* src = (i < 16384) ? (coord + i * 3)
                                   : (gt + (i - 16384) * 3);
    float x = src[0], y = src[1], z = src[2];
    packed[i] = make_float4(x, y, z, fmaf(x, x, fmaf(y, y, z * z)));
}

__global__ __launch_bounds__(512, 4) void chamfer_pass(
    const float4* __restrict__ packed, float* __restrict__ partials)
{
    __shared__ float4 sc[NPTS];    // exactly 64 KB; reused for block-sum at end

    const float4* pc = packed;            // coord, 4*4096
    const float4* pg = packed + 16384;    // gt,    4*4096

    int bx   = blockIdx.x;
    int pass = bx >> 8;            // 0: held=gt/stream=coord, 1: reverse
    int r    = bx & 255;
    int b    = r >> 6;
    int tile = r & 63;             // 64 tiles of 64 held pts

    const float4* hb = (pass ? pc : pg) + b * NPTS;
    const float4* sb = (pass ? pg : pc) + b * NPTS;

    int tid = threadIdx.x;
    int wv  = tid >> 6;            // 0..7: wave id
    int ph  = tid & 63;            // lane

    // ---- stage the whole stream into LDS (pure copy, already packed) ----
#pragma unroll
    for (int rr = 0; rr < 8; ++rr)
        sc[rr * 512 + tid] = sb[rr * 512 + tid];

    // ---- held points -> registers, folded as (-2x,-2y,-2z), |h|^2 ----
    // d^2 = h.w + (c.w + c.x*(-2hx) + c.y*(-2hy) + c.z*(-2hz))
    float hx[G], hy[G], hz[G], h2[G], mn[G];
    int h0 = tile * TILE + wv * G;
#pragma unroll
    for (int g = 0; g < G; ++g) {
        float4 h = hb[h0 + g];
        hx[g] = -2.f * h.x;
        hy[g] = -2.f * h.y;
        hz[g] = -2.f * h.z;
        h2[g] = h.w;
        mn[g] = INFINITY;
    }
    __syncthreads();               // stream fully staged; the only hot barrier

    // ---- all 4096 stream pts from LDS, 2 per lane per iter ----
#pragma unroll 8
    for (int it = 0; it < 32; ++it) {
        float4 c0 = sc[it * 128 + ph];
        float4 c1 = sc[it * 128 + 64 + ph];
#pragma unroll
        for (int g = 0; g < G; ++g) {
            float a = fmaf(c0.x, hx[g], c0.w);   // |c|^2 - 2 c.h
            a = fmaf(c0.y, hy[g], a);
            a = fmaf(c0.z, hz[g], a);
            float d = fmaf(c1.x, hx[g], c1.w);
            d = fmaf(c1.y, hy[g], d);
            d = fmaf(c1.z, hz[g], d);
            mn[g] = fminf(fminf(a, d), mn[g]);   // v_min3_f32
        }
    }

    // ---- min over 64 lanes, add |h|^2, sum over g ----
    float ssum = 0.f;
#pragma unroll
    for (int g = 0; g < G; ++g) {
        float v = mn[g];
        v = fminf(v, __shfl_xor(v, 32));
        v = fminf(v, __shfl_xor(v, 16));
        v = fminf(v, __shfl_xor(v, 8));
        v = fminf(v, __shfl_xor(v, 4));
        v = fminf(v, __shfl_xor(v, 2));
        v = fminf(v, __shfl_xor(v, 1));
        ssum += fmaxf(v + h2[g], 0.f);   // true d^2 >= 0; clamp fp cancellation
    }

    // block reduce: reuse sc (all reads done; barrier orders it)
    __syncthreads();
    float* red = (float*)sc;
    if (ph == 0) red[wv] = ssum;
    __syncthreads();
    if (tid == 0) {
        float t = 0.f;
#pragma unroll
        for (int k = 0; k < 8; ++k) t += red[k];
        partials[bx] = t;
    }
}

__global__ __launch_bounds__(256) void chamfer_final(
    const float* __restrict__ partials, float* __restrict__ out)
{
    __shared__ float wsum[4];
    int tid = threadIdx.x;
    float s = partials[tid] + partials[tid + 256];
#pragma unroll
    for (int off = 32; off > 0; off >>= 1)
        s += __shfl_down(s, off);
    if ((tid & 63) == 0) wsum[tid >> 6] = s;
    __syncthreads();
    if (tid == 0)
        out[0] = (wsum[0] + wsum[1] + wsum[2] + wsum[3]) * (1.0f / 16384.0f);
}

extern "C" void kernel_launch(void* const* d_in, const int* in_sizes, int n_in,
                              void* d_out, int out_size, void* d_ws, size_t ws_size,
                              hipStream_t stream) {
    const float* coord = (const float*)d_in[0];  // [4,4096,3]
    const float* gt    = (const float*)d_in[1];  // [4,4096,3]
    float4* packed   = (float4*)d_ws;                                  // 512 KB
    float*  partials = (float*)((char*)d_ws + 32768 * sizeof(float4)); // 512 floats
    float*  out      = (float*)d_out;

    chamfer_pack<<<128, 256, 0, stream>>>(coord, gt, packed);
    chamfer_pass<<<512, 512, 0, stream>>>(packed, partials);
    chamfer_final<<<1, 256, 0, stream>>>(partials, out);
}

// Round 5
// 67.985 us; speedup vs baseline: 1.0679x; 1.0673x over previous
//
#include <hip/hip_runtime.h>

// Chamfer distance v7: B=4, N=M=4096, D=3, fp32 in, scalar fp32 out.
//
// Measured accounting (R4..R6): timed window ~= 40 us poison fill (256 MB
// fillBufferAligned, harness, untouchable) + ~15-20 us of ~25 tiny restore
// dispatches + our kernels. R5 (pure-L2) == R6 (full-LDS) to 0.05% ==> pass
// structure is NOT the bottleneck; our kernels are near the ~6-8 us VALU
// floor (3 fma + 0.5 min3 per pair, fp32 — no fp32 MFMA exists, pk_fma
// issue rate gives no flop gain on gfx950). R4->R5/R6 delta (+2.1 us) ==
// one extra dispatch ==> ~2 us/dispatch.
//
// R7 = R6 with the pack kernel FUSED into the pass (2 kernels total):
//  - each block stages the raw stream cloud (48 KB, L2-resident) straight
//    into packed LDS float4 (x,y,z,|c|^2), stride-512 interleave so
//    ds_write_b128 is lane-contiguous (conflict-free);
//  - bit-identical math/accumulation order to R6 (absmax 0.0 expected);
//  - workspace use drops to 512 partial floats.
// Predicted: 72.6 -> ~69.5-70.5 us. If >=72: harness floor -> ROOFLINE.

#define NPTS 4096
#define TILE 64     // held points per block
#define G    8      // held points per wave (broadcast across 64 lanes)

__global__ __launch_bounds__(512, 4) void chamfer_pass(
    const float* __restrict__ coord, const float* __restrict__ gt,
    float* __restrict__ partials)
{
    __shared__ float4 sc[NPTS];    // exactly 64 KB; reused for block-sum at end

    int bx   = blockIdx.x;
    int pass = bx >> 8;            // 0: held=gt/stream=coord, 1: reverse
    int r    = bx & 255;
    int b    = r >> 6;
    int tile = r & 63;             // 64 tiles of 64 held pts

    const float* hbase = (pass ? coord : gt) + b * NPTS * 3;
    const float* sbase = (pass ? gt : coord) + b * NPTS * 3;

    int tid = threadIdx.x;
    int wv  = tid >> 6;            // 0..7: wave id
    int ph  = tid & 63;            // lane

    // ---- stage raw stream -> packed LDS (x,y,z,|c|^2) ----
    // stride-512 interleave: lane-contiguous ds_write_b128, conflict-free.
#pragma unroll
    for (int rr = 0; rr < 8; ++rr) {
        int p = rr * 512 + tid;
        const float* s0 = sbase + p * 3;
        float x = s0[0], y = s0[1], z = s0[2];
        sc[p] = make_float4(x, y, z, fmaf(x, x, fmaf(y, y, z * z)));
    }

    // ---- held points -> registers, folded as (-2x,-2y,-2z), |h|^2 ----
    // d^2 = h2 + (c.w + c.x*(-2hx) + c.y*(-2hy) + c.z*(-2hz))
    float hx[G], hy[G], hz[G], h2[G], mn[G];
    int h0 = tile * TILE + wv * G;
#pragma unroll
    for (int g = 0; g < G; ++g) {
        const float* hp = hbase + (h0 + g) * 3;
        float x = hp[0], y = hp[1], z = hp[2];
        hx[g] = -2.f * x;
        hy[g] = -2.f * y;
        hz[g] = -2.f * z;
        h2[g] = fmaf(x, x, fmaf(y, y, z * z));   // same formula as pack: bit-exact
        mn[g] = INFINITY;
    }
    __syncthreads();               // stream fully staged; the only hot barrier

    // ---- all 4096 stream pts from LDS, 2 per lane per iter ----
#pragma unroll 8
    for (int it = 0; it < 32; ++it) {
        float4 c0 = sc[it * 128 + ph];
        float4 c1 = sc[it * 128 + 64 + ph];
#pragma unroll
        for (int g = 0; g < G; ++g) {
            float a = fmaf(c0.x, hx[g], c0.w);   // |c|^2 - 2 c.h
            a = fmaf(c0.y, hy[g], a);
            a = fmaf(c0.z, hz[g], a);
            float d = fmaf(c1.x, hx[g], c1.w);
            d = fmaf(c1.y, hy[g], d);
            d = fmaf(c1.z, hz[g], d);
            mn[g] = fminf(fminf(a, d), mn[g]);   // v_min3_f32
        }
    }

    // ---- min over 64 lanes, add |h|^2, sum over g ----
    float ssum = 0.f;
#pragma unroll
    for (int g = 0; g < G; ++g) {
        float v = mn[g];
        v = fminf(v, __shfl_xor(v, 32));
        v = fminf(v, __shfl_xor(v, 16));
        v = fminf(v, __shfl_xor(v, 8));
        v = fminf(v, __shfl_xor(v, 4));
        v = fminf(v, __shfl_xor(v, 2));
        v = fminf(v, __shfl_xor(v, 1));
        ssum += fmaxf(v + h2[g], 0.f);   // true d^2 >= 0; clamp fp cancellation
    }

    // block reduce: reuse sc (all reads done; barrier orders it)
    __syncthreads();
    float* red = (float*)sc;
    if (ph == 0) red[wv] = ssum;
    __syncthreads();
    if (tid == 0) {
        float t = 0.f;
#pragma unroll
        for (int k = 0; k < 8; ++k) t += red[k];
        partials[bx] = t;
    }
}

__global__ __launch_bounds__(256) void chamfer_final(
    const float* __restrict__ partials, float* __restrict__ out)
{
    __shared__ float wsum[4];
    int tid = threadIdx.x;
    float s = partials[tid] + partials[tid + 256];
#pragma unroll
    for (int off = 32; off > 0; off >>= 1)
        s += __shfl_down(s, off);
    if ((tid & 63) == 0) wsum[tid >> 6] = s;
    __syncthreads();
    if (tid == 0)
        out[0] = (wsum[0] + wsum[1] + wsum[2] + wsum[3]) * (1.0f / 16384.0f);
}

extern "C" void kernel_launch(void* const* d_in, const int* in_sizes, int n_in,
                              void* d_out, int out_size, void* d_ws, size_t ws_size,
                              hipStream_t stream) {
    const float* coord = (const float*)d_in[0];  // [4,4096,3]
    const float* gt    = (const float*)d_in[1];  // [4,4096,3]
    float* partials = (float*)d_ws;              // 512 floats
    float* out      = (float*)d_out;

    chamfer_pass<<<512, 512, 0, stream>>>(coord, gt, partials);
    chamfer_final<<<1, 256, 0, stream>>>(partials, out);
}